// Round 6
// baseline (71.835 us; speedup 1.0000x reference)
//
#include <hip/hip_runtime.h>

typedef float f2 __attribute__((ext_vector_type(2)));
typedef float f4 __attribute__((ext_vector_type(4)));

static __device__ __forceinline__ f2 vexp2(f2 a) {
  f2 r;
  r.x = __builtin_amdgcn_exp2f(a.x);
  r.y = __builtin_amdgcn_exp2f(a.y);
  return r;
}

#define LOG2E 1.4426950408889634f

// Grid: 8(b) x 128(h) x 16(chunk of 4 channels) = 16384 blocks, 256 threads.
// Phase 0: stage padded x rows (3cin x 4r x 132wp) in LDS.
// Phase 1: compute k,v conv maps for the 4 chunk channels into LDS
//          (each tap reused by 4 output w-positions -> conv VALU / 4).
// Phase 2: lane w = t&127, cg = t>>7; each thread does 2 channels of
//          softmax math from LDS taps.
// Plain C++ vector math throughout (R4-proven). R5's inline-asm v_pk_*
// variant of this exact structure failed correctness (absmax 0.18) —
// do NOT reintroduce packed-math asm without disasm verification.
// launch_bounds(256,4): R2/R4-proven ~60 VGPR, no spill. NOTE: (256,8)
// forced a 32-VGPR budget and catastrophic scratch spills (R3).
__global__ __launch_bounds__(256, 4) void stem_kernel(
    const float* __restrict__ x,    // [8,3,128,128]
    const float* __restrict__ qwp,  // [64,3]
    const float* __restrict__ kwp,  // [64,3]
    const float* __restrict__ vwp,  // [64,3]
    const float* __restrict__ ea,   // [64,128]  (c, w)
    const float* __restrict__ eb,   // [64,128]  (c, h)
    const float* __restrict__ em,   // [64,128,128] (c, h, w)
    float* __restrict__ out)        // [8,64,128,128]
{
  __shared__ __align__(16) float xs[3][132][4];     // x[cin][wp][r], 6.3 KB
  __shared__ __align__(16) float kv[2][4][132][4];  // [k/v][c_loc][wp][r], 16.9 KB

  const int blk = blockIdx.x;
  const int cc  = (blk & 15) * 4;      // first channel of this 4-channel chunk
  const int h   = (blk >> 4) & 127;
  const int b   = blk >> 11;
  const int t   = threadIdx.x;

  // ---- Phase 0: stage x, zero-padded. idx = (cin*4 + r)*132 + wp so global
  // reads are coalesced along wp for fixed (cin, r).
  for (int idx = t; idx < 1584; idx += 256) {
    int wp  = idx % 132;
    int rem = idx / 132;
    int r   = rem & 3;
    int cin = rem >> 2;
    int sr = h - 2 + r, sc = wp - 2;
    float val = 0.0f;
    if ((unsigned)sr < 128u && (unsigned)sc < 128u)
      val = x[((b * 3 + cin) * 128 + sr) * 128 + sc];
    xs[cin][wp][r] = val;
  }
  __syncthreads();

  // ---- Phase 1: k,v conv maps. Task = (c_loc, wp): 4 rows at once (b128 io).
  for (int idx = t; idx < 528; idx += 256) {
    int wp = idx % 132;
    int cl = idx / 132;
    int c  = cc + cl;
    f4 x0 = *(const f4*)&xs[0][wp][0];
    f4 x1 = *(const f4*)&xs[1][wp][0];
    f4 x2 = *(const f4*)&xs[2][wp][0];
    float ka = kwp[c * 3 + 0], kb = kwp[c * 3 + 1], kc = kwp[c * 3 + 2];
    float va = vwp[c * 3 + 0], vb = vwp[c * 3 + 1], vc = vwp[c * 3 + 2];
    f4 km = ka * x0 + kb * x1 + kc * x2;
    f4 vm = va * x0 + vb * x1 + vc * x2;
    *(f4*)&kv[0][cl][wp][0] = km;
    *(f4*)&kv[1][cl][wp][0] = vm;
  }
  __syncthreads();

  // ---- Phase 2
  const int w  = t & 127;
  const int cg = t >> 7;   // wave-uniform

  // x at (h, w) for the q conv: col w+2, row r=2
  const float xq0 = xs[0][w + 2][2];
  const float xq1 = xs[1][w + 2][2];
  const float xq2 = xs[2][w + 2][2];

#pragma unroll 1
  for (int i = 0; i < 2; ++i) {
    const int cl = cg * 2 + i;
    const int c  = __builtin_amdgcn_readfirstlane(cc + cl);  // -> s_loads

    // v taps: 4 x ds_read_b128, lane-contiguous stride-16B (conflict-free)
    f2 vv[8];
#pragma unroll
    for (int j = 0; j < 4; ++j) {
      f4 v4 = *(const f4*)&kv[1][cl][w + j][0];
      vv[2 * j]     = f2{v4.x, v4.y};
      vv[2 * j + 1] = f2{v4.z, v4.w};
    }

    const float q = qwp[c * 3 + 0] * xq0 + qwp[c * 3 + 1] * xq1 +
                    qwp[c * 3 + 2] * xq2;
    const float sp =
        (ea[c * 128 + w] + eb[c * 128 + h]) * em[(c * 128 + h) * 128 + w] * LOG2E;

    // embedding logits tl = sp * v^2 (log2 domain), stored in e[]
    f2 e[8];
#pragma unroll
    for (int u = 0; u < 8; ++u) e[u] = (sp * vv[u]) * vv[u];

    // max over 16 (nested fmaxf to invite v_max3_f32)
    float tmax = fmaxf(fmaxf(fmaxf(e[0].x, e[0].y), fmaxf(e[1].x, e[1].y)),
                       fmaxf(fmaxf(e[2].x, e[2].y), fmaxf(e[3].x, e[3].y)));
    tmax = fmaxf(tmax, fmaxf(fmaxf(e[4].x, e[4].y), fmaxf(e[5].x, e[5].y)));
    tmax = fmaxf(tmax, fmaxf(fmaxf(e[6].x, e[6].y), fmaxf(e[7].x, e[7].y)));

    // e = 2^(tl - tmax); embedding-softmax normalization folded into qs
#pragma unroll
    for (int u = 0; u < 8; ++u) e[u] = vexp2(e[u] - tmax);

    f2 se = ((e[0] + e[1]) + (e[2] + e[3])) + ((e[4] + e[5]) + (e[6] + e[7]));
    const float sum_e = se.x + se.y;
    const float qs = q * LOG2E * __builtin_amdgcn_rcpf(sum_e);

    // att: p = 2^(qs * k * e); |arg| <~ 4 so no max-subtraction needed.
    // k taps read late (4 x b128) to cap live registers.
    f2 ps = f2{0.0f, 0.0f}, pv = f2{0.0f, 0.0f};
#pragma unroll
    for (int j = 0; j < 4; ++j) {
      f4 k4 = *(const f4*)&kv[0][cl][w + j][0];
      f2 p0 = vexp2((qs * f2{k4.x, k4.y}) * e[2 * j]);
      f2 p1 = vexp2((qs * f2{k4.z, k4.w}) * e[2 * j + 1]);
      ps = ps + p0 + p1;
      pv = pv + p0 * vv[2 * j];
      pv = pv + p1 * vv[2 * j + 1];
    }

    out[((b * 64 + c) * 128 + h) * 128 + w] =
        (pv.x + pv.y) * __builtin_amdgcn_rcpf(ps.x + ps.y);
  }
}

extern "C" void kernel_launch(void* const* d_in, const int* in_sizes, int n_in,
                              void* d_out, int out_size, void* d_ws, size_t ws_size,
                              hipStream_t stream) {
  const float* x  = (const float*)d_in[0];
  const float* qw = (const float*)d_in[1];
  const float* kw = (const float*)d_in[2];
  const float* vw = (const float*)d_in[3];
  const float* ea = (const float*)d_in[4];
  const float* eb = (const float*)d_in[5];
  const float* em = (const float*)d_in[6];
  float* out = (float*)d_out;

  stem_kernel<<<dim3(8 * 128 * 16), dim3(256), 0, stream>>>(x, qw, kw, vw, ea, eb, em, out);
}